// Round 4
// baseline (19353.447 us; speedup 1.0000x reference)
//
#include <hip/hip_runtime.h>
#include <hip/hip_bf16.h>
#include <hip/hip_cooperative_groups.h>

namespace cg = cooperative_groups;

#define Bn 64
#define Sn 256
#define Cn 512
#define Hn 1024
#define On 1024
#define NL 3        // L-1 inner layers

// ------------------------------------------------------------------
// prep: h_initT[l][b][k] = hid_layer[b][l+1][k]   (b-major, k contiguous)
// ------------------------------------------------------------------
__global__ void prep_kernel(const float* __restrict__ hid, float* __restrict__ h_initT) {
    int q = blockIdx.x * blockDim.x + threadIdx.x;       // float4 id
    if (q >= NL * Bn * (Hn / 4)) return;
    int k4 = (q & 255) * 4;
    int b  = (q >> 8) & 63;
    int l  = q >> 14;
    *(float4*)&h_initT[((size_t)l * Bn + b) * Hn + k4] =
        *(const float4*)&hid[(size_t)b * 4 * Hn + (size_t)(l + 1) * Hn + k4];
}

// ------------------------------------------------------------------
// G1: h0proj[b][g] = fc1_b[g] + sum_h h0[b][h] * fc1_w[g][512+h]
// ------------------------------------------------------------------
__global__ __launch_bounds__(256) void g1_kernel(const float* __restrict__ hid,
                                                 const float* __restrict__ fc1_w,
                                                 const float* __restrict__ fc1_b,
                                                 float* __restrict__ h0proj) {
    __shared__ __align__(16) float h0s[Hn];
    int b = blockIdx.x;
    int tid = threadIdx.x;
    for (int i = tid; i < Hn; i += 256) h0s[i] = hid[(size_t)b * 4 * Hn + i];
    __syncthreads();
    for (int g = tid; g < Hn; g += 256) {
        const float* wr = fc1_w + (size_t)g * (Cn + Hn) + Cn;
        float acc = 0.f;
        for (int k = 0; k < Hn; k += 4) {
            float4 w4 = *(const float4*)&wr[k];
            acc = fmaf(w4.x, h0s[k + 0], acc);
            acc = fmaf(w4.y, h0s[k + 1], acc);
            acc = fmaf(w4.z, h0s[k + 2], acc);
            acc = fmaf(w4.w, h0s[k + 3], acc);
        }
        h0proj[b * Hn + g] = acc + fc1_b[g];
    }
}

// ------------------------------------------------------------------
// G2: tb[t][g][b] = bf16( tanh( X[t,b,:512]@fc1_w[g,:512] + h0proj[b][g] ) )
// ------------------------------------------------------------------
__global__ __launch_bounds__(256) void g2_kernel(const float* __restrict__ x,
                                                 const float* __restrict__ fc1_w,
                                                 const float* __restrict__ h0proj,
                                                 __hip_bfloat16* __restrict__ tb) {
    __shared__ __align__(16) float As[64][64];   // [k][b]
    __shared__ __align__(16) float Bs[64][64];   // [k][g]
    int tid = threadIdx.x;
    int bx = blockIdx.x;          // = t
    int g0 = blockIdx.y * 64;
    int ml = tid & 63;
    int kq = tid >> 6;
    const float* xrow = x + (size_t)ml * (Sn * Cn) + (size_t)bx * Cn;
    const float* wrow = fc1_w + (size_t)(g0 + ml) * (Cn + Hn);
    int wave = tid >> 6, lane = tid & 63;
    int tm = (wave & 1) * 32 + (lane & 7) * 4;   // b
    int tg = (wave >> 1) * 32 + (lane >> 3) * 4; // g
    float acc[4][4] = {};
    for (int kc = 0; kc < Cn / 64; ++kc) {
#pragma unroll
        for (int r = 0; r < 4; ++r) {
            int kk = kq * 16 + r * 4;
            float4 v = *(const float4*)&xrow[kc * 64 + kk];
            As[kk + 0][ml] = v.x; As[kk + 1][ml] = v.y;
            As[kk + 2][ml] = v.z; As[kk + 3][ml] = v.w;
        }
#pragma unroll
        for (int r = 0; r < 4; ++r) {
            int kk = kq * 16 + r * 4;
            float4 v = *(const float4*)&wrow[kc * 64 + kk];
            Bs[kk + 0][ml] = v.x; Bs[kk + 1][ml] = v.y;
            Bs[kk + 2][ml] = v.z; Bs[kk + 3][ml] = v.w;
        }
        __syncthreads();
#pragma unroll 4
        for (int k = 0; k < 64; ++k) {
            float4 a4 = *(const float4*)&As[k][tm];
            float4 b4 = *(const float4*)&Bs[k][tg];
            float av[4] = {a4.x, a4.y, a4.z, a4.w};
            float bv[4] = {b4.x, b4.y, b4.z, b4.w};
#pragma unroll
            for (int i = 0; i < 4; ++i)
#pragma unroll
                for (int j = 0; j < 4; ++j)
                    acc[i][j] = fmaf(av[i], bv[j], acc[i][j]);
        }
        __syncthreads();
    }
#pragma unroll
    for (int j = 0; j < 4; ++j) {
        int g = g0 + tg + j;
        union { ushort4 u4; __hip_bfloat16 h[4]; } cv;
#pragma unroll
        for (int i = 0; i < 4; ++i) {
            float hp = h0proj[(size_t)(tm + i) * Hn + g];
            cv.h[i] = __float2bfloat16(tanhf(acc[i][j] + hp));
        }
        *(ushort4*)&tb[((size_t)bx * Hn + g) * 64 + tm] = cv.u4;
    }
}

// ------------------------------------------------------------------
// G3: logits[m][o] = relu( temp[m][:] @ fc2_w[o][:] + fc2_b[o] ), temp = bf16 tb[t][g][b]
// ------------------------------------------------------------------
__global__ __launch_bounds__(256) void g3_kernel(const __hip_bfloat16* __restrict__ tb,
                                                 const float* __restrict__ fc2_w,
                                                 const float* __restrict__ fc2_b,
                                                 float* __restrict__ logits) {
    __shared__ __align__(16) float As[64][64];   // [k][m]
    __shared__ __align__(16) float Bs[64][64];   // [k][g]
    int tid = threadIdx.x;
    int bx = blockIdx.x;          // = t
    int g0 = blockIdx.y * 64;
    int ml = tid & 63;
    int kq = tid >> 6;
    const float* wrow = fc2_w + (size_t)(g0 + ml) * Hn;
    int wave = tid >> 6, lane = tid & 63;
    int tm = (wave & 1) * 32 + (lane & 7) * 4;
    int tg = (wave >> 1) * 32 + (lane >> 3) * 4;
    float acc[4][4] = {};
    for (int kc = 0; kc < Hn / 64; ++kc) {
        for (int e = tid; e < 4096; e += 256) {
            int kk = e >> 6, mm = e & 63;
            As[kk][mm] = __bfloat162float(tb[((size_t)bx * Hn + kc * 64 + kk) * 64 + mm]);
        }
#pragma unroll
        for (int r = 0; r < 4; ++r) {
            int kk = kq * 16 + r * 4;
            float4 v = *(const float4*)&wrow[kc * 64 + kk];
            Bs[kk + 0][ml] = v.x; Bs[kk + 1][ml] = v.y;
            Bs[kk + 2][ml] = v.z; Bs[kk + 3][ml] = v.w;
        }
        __syncthreads();
#pragma unroll 4
        for (int k = 0; k < 64; ++k) {
            float4 a4 = *(const float4*)&As[k][tm];
            float4 b4 = *(const float4*)&Bs[k][tg];
            float av[4] = {a4.x, a4.y, a4.z, a4.w};
            float bv[4] = {b4.x, b4.y, b4.z, b4.w};
#pragma unroll
            for (int i = 0; i < 4; ++i)
#pragma unroll
                for (int j = 0; j < 4; ++j)
                    acc[i][j] = fmaf(av[i], bv[j], acc[i][j]);
        }
        __syncthreads();
    }
    int m0 = bx * 64;
#pragma unroll
    for (int i = 0; i < 4; ++i) {
        int m = m0 + tm + i;
        float4 o;
        o.x = fmaxf(acc[i][0] + fc2_b[g0 + tg + 0], 0.f);
        o.y = fmaxf(acc[i][1] + fc2_b[g0 + tg + 1], 0.f);
        o.z = fmaxf(acc[i][2] + fc2_b[g0 + tg + 2], 0.f);
        o.w = fmaxf(acc[i][3] + fc2_b[g0 + tg + 3], 0.f);
        *(float4*)&logits[(size_t)m * Hn + g0 + tg] = o;
    }
}

// ==================================================================
// recur3: step-by-step f32 recurrence. 192 WGs x 512 thr.
// WG = (l, 16-row slice). W rows in registers (128 VGPR/thread).
// h layout: hbufT[parity][l][b][k] (k contiguous). LDS: 2x32KB h-chunk dbuf.
// Thread tile: 4 rows x 32 k (as 8 chunks x 4) x 16 b; kg-reduce by shfl.
// One grid.sync per step; fold(t-1) overlapped into step t.
// ==================================================================
__global__ __launch_bounds__(512, 2) void recur3_kernel(
        const float* __restrict__ lin_w, const float* __restrict__ lin_b,
        const float* __restrict__ h_initT, __hip_bfloat16* __restrict__ tb,
        float* __restrict__ hbufT) {
    __shared__ __align__(16) float hs[2][8192];      // [buf][b*128 + kloc], 64 KB
    const int tid = threadIdx.x;
    const int w = blockIdx.x;
    const int l = w >> 6;
    const int g0 = (w & 63) * 16;
    const int kg = tid & 31;
    const int rg = (tid >> 5) & 3;
    const int bg = tid >> 7;                          // 0..3
    const int lane = tid & 63;
    const size_t LSZ = (size_t)Hn * Bn;               // 65536
    const size_t PSZ = (size_t)NL * LSZ;              // 196608

    // ---- W rows -> registers (once) ----
    float4 wreg[32];                                  // [j*4 + rr]
    {
        const float* wb = lin_w + ((size_t)l * Hn + g0 + rg * 4) * Hn + kg * 4;
#pragma unroll
        for (int j = 0; j < 8; ++j)
#pragma unroll
            for (int rr = 0; rr < 4; ++rr)
                wreg[j * 4 + rr] = *(const float4*)(wb + (size_t)rr * Hn + j * 128);
    }
    float bias_r[4];
#pragma unroll
    for (int rr = 0; rr < 4; ++rr) bias_r[rr] = lin_b[l * Hn + g0 + rg * 4 + rr];

    cg::grid_group grid = cg::this_grid();

    for (int p = 0; p < Sn; ++p) {
        const float* src = (p == 0) ? (h_initT + (size_t)l * LSZ)
                                    : (hbufT + (size_t)((p + 1) & 1) * PSZ + (size_t)l * LSZ);
        float* dst = hbufT + (size_t)(p & 1) * PSZ + (size_t)l * LSZ;

        // ---- fold(t = p-1): temp = tanh(h2 + tanh(h1 + tanh(h0 + t0))) ----
        if (p > 0) {
            int e = w * 512 + tid;
            if (e < 65536) {
                int g = e & 1023, b = e >> 10;
                const float* hb = hbufT + (size_t)((p + 1) & 1) * PSZ;  // parity (p-1)&1
                size_t off = (size_t)b * Hn + g;
                size_t tix = ((size_t)(p - 1) * Hn + g) * 64 + b;
                float tv = __bfloat162float(tb[tix]);
                tv = tanhf(hb[off] + tv);
                tv = tanhf(hb[LSZ + off] + tv);
                tv = tanhf(hb[2 * LSZ + off] + tv);
                tb[tix] = __float2bfloat16(tv);
            }
        }

        // ---- stage chunk 0 ----
        float4 st[4];
#pragma unroll
        for (int i = 0; i < 4; ++i) {
            int q = tid + i * 512;
            int b = q >> 5, kq = (q & 31) * 4;
            st[i] = *(const float4*)(src + (size_t)b * Hn + kq);
        }
#pragma unroll
        for (int i = 0; i < 4; ++i)
            *(float4*)&hs[0][(tid + i * 512) * 4] = st[i];
        __syncthreads();

        float acc[4][16];
#pragma unroll
        for (int rr = 0; rr < 4; ++rr)
#pragma unroll
            for (int bb = 0; bb < 16; ++bb) acc[rr][bb] = 0.f;

#pragma unroll
        for (int j = 0; j < 8; ++j) {
            if (j < 7) {                              // prefetch chunk j+1 (T14)
#pragma unroll
                for (int i = 0; i < 4; ++i) {
                    int q = tid + i * 512;
                    int b = q >> 5, kq = (q & 31) * 4;
                    st[i] = *(const float4*)(src + (size_t)b * Hn + (j + 1) * 128 + kq);
                }
            }
            const float* hbse = hs[j & 1];
#pragma unroll
            for (int bb = 0; bb < 16; ++bb) {
                float4 h4 = *(const float4*)&hbse[(bg * 16 + bb) * 128 + kg * 4];
#pragma unroll
                for (int rr = 0; rr < 4; ++rr) {
                    float4 wv = wreg[j * 4 + rr];
                    acc[rr][bb] = fmaf(wv.x, h4.x, acc[rr][bb]);
                    acc[rr][bb] = fmaf(wv.y, h4.y, acc[rr][bb]);
                    acc[rr][bb] = fmaf(wv.z, h4.z, acc[rr][bb]);
                    acc[rr][bb] = fmaf(wv.w, h4.w, acc[rr][bb]);
                }
            }
            if (j < 7) {
#pragma unroll
                for (int i = 0; i < 4; ++i)
                    *(float4*)&hs[(j + 1) & 1][(tid + i * 512) * 4] = st[i];
            }
            __syncthreads();
        }

        // ---- reduce over kg (32 lanes) and store ----
#pragma unroll
        for (int rr = 0; rr < 4; ++rr)
#pragma unroll
            for (int bb = 0; bb < 16; ++bb) {
                float v = acc[rr][bb];
                v += __shfl_xor(v, 1);
                v += __shfl_xor(v, 2);
                v += __shfl_xor(v, 4);
                v += __shfl_xor(v, 8);
                v += __shfl_xor(v, 16);
                acc[rr][bb] = v;
            }
        if ((lane & 31) == 0) {
#pragma unroll
            for (int rr = 0; rr < 4; ++rr)
#pragma unroll
                for (int bb = 0; bb < 16; ++bb)
                    dst[(size_t)(bg * 16 + bb) * Hn + g0 + rg * 4 + rr] = acc[rr][bb] + bias_r[rr];
        }
        grid.sync();
    }

    // ---- final fold t = Sn-1 ----
    {
        int e = w * 512 + tid;
        if (e < 65536) {
            int g = e & 1023, b = e >> 10;
            const float* hb = hbufT + (size_t)((Sn - 1) & 1) * PSZ;
            size_t off = (size_t)b * Hn + g;
            size_t tix = ((size_t)(Sn - 1) * Hn + g) * 64 + b;
            float tv = __bfloat162float(tb[tix]);
            tv = tanhf(hb[off] + tv);
            tv = tanhf(hb[LSZ + off] + tv);
            tv = tanhf(hb[2 * LSZ + off] + tv);
            tb[tix] = __float2bfloat16(tv);
        }
    }
}

// ------------------------------------------------------------------
// softmax over each 1024-row of logits -> f32 out
// ------------------------------------------------------------------
__global__ __launch_bounds__(256) void softmax_kernel(const float* __restrict__ logits,
                                                      float* __restrict__ out) {
    __shared__ float redm[4];
    __shared__ float reds[4];
    __shared__ float bcast[2];
    int row = blockIdx.x, tid = threadIdx.x;
    const float* in = logits + (size_t)row * On;
    float4 v = *(const float4*)&in[tid * 4];
    float mx = fmaxf(fmaxf(v.x, v.y), fmaxf(v.z, v.w));
#pragma unroll
    for (int o = 32; o > 0; o >>= 1) mx = fmaxf(mx, __shfl_down(mx, o));
    if ((tid & 63) == 0) redm[tid >> 6] = mx;
    __syncthreads();
    if (tid == 0) bcast[0] = fmaxf(fmaxf(redm[0], redm[1]), fmaxf(redm[2], redm[3]));
    __syncthreads();
    float M = bcast[0];
    float e0 = expf(v.x - M), e1 = expf(v.y - M), e2 = expf(v.z - M), e3 = expf(v.w - M);
    float s = e0 + e1 + e2 + e3;
#pragma unroll
    for (int o = 32; o > 0; o >>= 1) s += __shfl_down(s, o);
    if ((tid & 63) == 0) reds[tid >> 6] = s;
    __syncthreads();
    if (tid == 0) bcast[1] = reds[0] + reds[1] + reds[2] + reds[3];
    __syncthreads();
    float inv = 1.0f / bcast[1];
    float4 o4 = make_float4(e0 * inv, e1 * inv, e2 * inv, e3 * inv);
    *(float4*)&out[(size_t)row * On + tid * 4] = o4;
}

// ------------------------------------------------------------------
extern "C" void kernel_launch(void* const* d_in, const int* in_sizes, int n_in,
                              void* d_out, int out_size, void* d_ws, size_t ws_size,
                              hipStream_t stream) {
    const float* x     = (const float*)d_in[0];
    const float* hid   = (const float*)d_in[1];
    const float* fc1_w = (const float*)d_in[2];
    const float* fc1_b = (const float*)d_in[3];
    const float* fc2_w = (const float*)d_in[4];
    const float* fc2_b = (const float*)d_in[5];
    const float* lin_w = (const float*)d_in[6];
    const float* lin_b = (const float*)d_in[7];
    float* out = (float*)d_out;

    char* wsb = (char*)d_ws;
    __hip_bfloat16* tb = (__hip_bfloat16*)wsb;                  // 32 MB  [t][g][b]
    float* logits = (float*)(wsb + (size_t)33554432);           // 64 MB
    float* hbufT  = (float*)(wsb + (size_t)33554432 + 67108864);            // 1.5 MB
    float* h_initT = hbufT + (size_t)2 * NL * Hn * Bn;          // 0.75 MB
    float* h0proj  = h_initT + (size_t)NL * Hn * Bn;            // 0.25 MB

    prep_kernel<<<192, 256, 0, stream>>>(hid, h_initT);
    g1_kernel<<<Bn, 256, 0, stream>>>(hid, fc1_w, fc1_b, h0proj);
    g2_kernel<<<dim3(Sn, Hn / 64), 256, 0, stream>>>(x, fc1_w, h0proj, tb);

    void* args[] = { (void*)&lin_w, (void*)&lin_b, (void*)&h_initT, (void*)&tb,
                     (void*)&hbufT };
    hipLaunchCooperativeKernel((const void*)recur3_kernel, dim3(192), dim3(512),
                               args, 0, stream);

    g3_kernel<<<dim3(Sn, Hn / 64), 256, 0, stream>>>(tb, fc2_w, fc2_b, logits);
    softmax_kernel<<<Sn * Bn, 256, 0, stream>>>(logits, out);
}

// Round 6
// 5109.182 us; speedup vs baseline: 3.7880x; 3.7880x over previous
//
#include <hip/hip_runtime.h>
#include <hip/hip_bf16.h>

#define Bn 64
#define Sn 256
#define Cn 512
#define Hn 1024
#define On 1024
#define NL 3

// ------------------------------------------------------------------
// prep: h0T[l][k][b] = hid[b][l+1][k]  (64x64 LDS tile transpose)
// ------------------------------------------------------------------
__global__ __launch_bounds__(256) void prep_kernel(const float* __restrict__ hid,
                                                   float* __restrict__ h0T) {
    __shared__ float T[64][65];
    int l = blockIdx.x >> 4;
    int kb = (blockIdx.x & 15) * 64;
    int tid = threadIdx.x;
    for (int e = tid; e < 1024; e += 256) {
        int b = e >> 4, k4 = (e & 15) * 4;
        float4 v = *(const float4*)&hid[(size_t)b * 4096 + (size_t)(l + 1) * 1024 + kb + k4];
        T[b][k4] = v.x; T[b][k4 + 1] = v.y; T[b][k4 + 2] = v.z; T[b][k4 + 3] = v.w;
    }
    __syncthreads();
    for (int e = tid; e < 1024; e += 256) {
        int k = e >> 4, b4 = (e & 15) * 4;
        float4 v = make_float4(T[b4][k], T[b4 + 1][k], T[b4 + 2][k], T[b4 + 3][k]);
        *(float4*)&h0T[(size_t)l * 65536 + (size_t)(kb + k) * 64 + b4] = v;
    }
}

// ------------------------------------------------------------------
// G1: h0proj[b][g] = fc1_b[g] + sum_h h0[b][h] * fc1_w[g][512+h]
// ------------------------------------------------------------------
__global__ __launch_bounds__(256) void g1_kernel(const float* __restrict__ hid,
                                                 const float* __restrict__ fc1_w,
                                                 const float* __restrict__ fc1_b,
                                                 float* __restrict__ h0proj) {
    __shared__ __align__(16) float h0s[Hn];
    int b = blockIdx.x;
    int tid = threadIdx.x;
    for (int i = tid; i < Hn; i += 256) h0s[i] = hid[(size_t)b * 4 * Hn + i];
    __syncthreads();
    for (int g = tid; g < Hn; g += 256) {
        const float* wr = fc1_w + (size_t)g * (Cn + Hn) + Cn;
        float acc = 0.f;
        for (int k = 0; k < Hn; k += 4) {
            float4 w4 = *(const float4*)&wr[k];
            acc = fmaf(w4.x, h0s[k + 0], acc);
            acc = fmaf(w4.y, h0s[k + 1], acc);
            acc = fmaf(w4.z, h0s[k + 2], acc);
            acc = fmaf(w4.w, h0s[k + 3], acc);
        }
        h0proj[b * Hn + g] = acc + fc1_b[g];
    }
}

// ------------------------------------------------------------------
// G2: tb[t][g][b] = bf16( tanh( X[t,b,:512]@fc1_w[g,:512] + h0proj[b][g] ) )
// ------------------------------------------------------------------
__global__ __launch_bounds__(256) void g2_kernel(const float* __restrict__ x,
                                                 const float* __restrict__ fc1_w,
                                                 const float* __restrict__ h0proj,
                                                 __hip_bfloat16* __restrict__ tb) {
    __shared__ __align__(16) float As[64][64];
    __shared__ __align__(16) float Bs[64][64];
    int tid = threadIdx.x;
    int bx = blockIdx.x;
    int g0 = blockIdx.y * 64;
    int ml = tid & 63;
    int kq = tid >> 6;
    const float* xrow = x + (size_t)ml * (Sn * Cn) + (size_t)bx * Cn;
    const float* wrow = fc1_w + (size_t)(g0 + ml) * (Cn + Hn);
    int wave = tid >> 6, lane = tid & 63;
    int tm = (wave & 1) * 32 + (lane & 7) * 4;
    int tg = (wave >> 1) * 32 + (lane >> 3) * 4;
    float acc[4][4] = {};
    for (int kc = 0; kc < Cn / 64; ++kc) {
#pragma unroll
        for (int r = 0; r < 4; ++r) {
            int kk = kq * 16 + r * 4;
            float4 v = *(const float4*)&xrow[kc * 64 + kk];
            As[kk + 0][ml] = v.x; As[kk + 1][ml] = v.y;
            As[kk + 2][ml] = v.z; As[kk + 3][ml] = v.w;
        }
#pragma unroll
        for (int r = 0; r < 4; ++r) {
            int kk = kq * 16 + r * 4;
            float4 v = *(const float4*)&wrow[kc * 64 + kk];
            Bs[kk + 0][ml] = v.x; Bs[kk + 1][ml] = v.y;
            Bs[kk + 2][ml] = v.z; Bs[kk + 3][ml] = v.w;
        }
        __syncthreads();
#pragma unroll 4
        for (int k = 0; k < 64; ++k) {
            float4 a4 = *(const float4*)&As[k][tm];
            float4 b4 = *(const float4*)&Bs[k][tg];
            float av[4] = {a4.x, a4.y, a4.z, a4.w};
            float bv[4] = {b4.x, b4.y, b4.z, b4.w};
#pragma unroll
            for (int i = 0; i < 4; ++i)
#pragma unroll
                for (int j = 0; j < 4; ++j)
                    acc[i][j] = fmaf(av[i], bv[j], acc[i][j]);
        }
        __syncthreads();
    }
#pragma unroll
    for (int j = 0; j < 4; ++j) {
        int g = g0 + tg + j;
        union { ushort4 u4; __hip_bfloat16 h[4]; } cv;
#pragma unroll
        for (int i = 0; i < 4; ++i) {
            float hp = h0proj[(size_t)(tm + i) * Hn + g];
            cv.h[i] = __float2bfloat16(tanhf(acc[i][j] + hp));
        }
        *(ushort4*)&tb[((size_t)bx * Hn + g) * 64 + tm] = cv.u4;
    }
}

// ------------------------------------------------------------------
// G3: logits[m][o] = relu( temp[m][:] @ fc2_w[o][:] + fc2_b[o] )
// ------------------------------------------------------------------
__global__ __launch_bounds__(256) void g3_kernel(const __hip_bfloat16* __restrict__ tb,
                                                 const float* __restrict__ fc2_w,
                                                 const float* __restrict__ fc2_b,
                                                 float* __restrict__ logits) {
    __shared__ __align__(16) float As[64][64];
    __shared__ __align__(16) float Bs[64][64];
    int tid = threadIdx.x;
    int bx = blockIdx.x;
    int g0 = blockIdx.y * 64;
    int ml = tid & 63;
    int kq = tid >> 6;
    const float* wrow = fc2_w + (size_t)(g0 + ml) * Hn;
    int wave = tid >> 6, lane = tid & 63;
    int tm = (wave & 1) * 32 + (lane & 7) * 4;
    int tg = (wave >> 1) * 32 + (lane >> 3) * 4;
    float acc[4][4] = {};
    for (int kc = 0; kc < Hn / 64; ++kc) {
        for (int e = tid; e < 4096; e += 256) {
            int kk = e >> 6, mm = e & 63;
            As[kk][mm] = __bfloat162float(tb[((size_t)bx * Hn + kc * 64 + kk) * 64 + mm]);
        }
#pragma unroll
        for (int r = 0; r < 4; ++r) {
            int kk = kq * 16 + r * 4;
            float4 v = *(const float4*)&wrow[kc * 64 + kk];
            Bs[kk + 0][ml] = v.x; Bs[kk + 1][ml] = v.y;
            Bs[kk + 2][ml] = v.z; Bs[kk + 3][ml] = v.w;
        }
        __syncthreads();
#pragma unroll 4
        for (int k = 0; k < 64; ++k) {
            float4 a4 = *(const float4*)&As[k][tm];
            float4 b4 = *(const float4*)&Bs[k][tg];
            float av[4] = {a4.x, a4.y, a4.z, a4.w};
            float bv[4] = {b4.x, b4.y, b4.z, b4.w};
#pragma unroll
            for (int i = 0; i < 4; ++i)
#pragma unroll
                for (int j = 0; j < 4; ++j)
                    acc[i][j] = fmaf(av[i], bv[j], acc[i][j]);
        }
        __syncthreads();
    }
    int m0 = bx * 64;
#pragma unroll
    for (int i = 0; i < 4; ++i) {
        int m = m0 + tm + i;
        float4 o;
        o.x = fmaxf(acc[i][0] + fc2_b[g0 + tg + 0], 0.f);
        o.y = fmaxf(acc[i][1] + fc2_b[g0 + tg + 1], 0.f);
        o.z = fmaxf(acc[i][2] + fc2_b[g0 + tg + 2], 0.f);
        o.w = fmaxf(acc[i][3] + fc2_b[g0 + tg + 3], 0.f);
        *(float4*)&logits[(size_t)m * Hn + g0 + tg] = o;
    }
}

// ------------------------------------------------------------------
// cvec: out[r] = sum_m A[r][m] * vecB[l(r)*1024 + m] + addB[r]
// wave per row, grid 768 x 256
// ------------------------------------------------------------------
__global__ __launch_bounds__(256) void cvec_kernel(const float* __restrict__ A,
                                                   const float* __restrict__ vecB,
                                                   const float* __restrict__ addB,
                                                   float* __restrict__ outv) {
    int row = blockIdx.x * 4 + (threadIdx.x >> 6);
    int lane = threadIdx.x & 63;
    int l = row >> 10;
    const float* ar = A + (size_t)row * Hn;
    const float* vb = vecB + (size_t)l * Hn;
    float s = 0.f;
#pragma unroll 4
    for (int j = 0; j < 16; ++j) {
        int k = lane + j * 64;
        s = fmaf(ar[k], vb[k], s);
    }
    s += __shfl_xor(s, 1);  s += __shfl_xor(s, 2);  s += __shfl_xor(s, 4);
    s += __shfl_xor(s, 8);  s += __shfl_xor(s, 16); s += __shfl_xor(s, 32);
    if (lane == 0) outv[row] = s + addB[row];
}

// ==================================================================
// gsl: C[3072 rows x ncols] (+= addRow) = A(scalar-loaded rows) * B
// 192 WGs x 512 thr; 16 rows/WG; thread tile 4r x 2c, full-K f32.
// B staged via 2x16x256 LDS double buffer w/ register prefetch.
// Optional fused fold batch (reads Xf, updates tb) at kernel head.
// Launch-per-superstep replaces cooperative grid.sync.
// ==================================================================
__global__ __launch_bounds__(512, 2) void gsl_kernel(
        const float* __restrict__ A,          // [3072][1024] flat
        const float* __restrict__ Bsrc,       // + l*bPanel + k*bstride + bcol0 + c
        unsigned long long bPanel, int bstride, int bcol0, int ncols,
        float* __restrict__ dst, int dstride, int dcol0,
        const float* __restrict__ addRow,     // [3072] or nullptr
        __hip_bfloat16* __restrict__ tb, const float* __restrict__ Xf,
        int folds, int do_gemm) {
    __shared__ __align__(16) float Bsh[2][16][256];   // 32 KB
    const int tid = threadIdx.x;
    const int wg  = blockIdx.x;                       // 192
    const int g0  = wg * 16;
    const int l   = g0 >> 10;

    // ---- fused fold(t = 4*folds + tp): temp = tanh(h2+tanh(h1+tanh(h0+t0))) ----
    if (folds >= 0) {
        for (int e = wg * 512 + tid; e < 4 * Hn * Bn; e += 192 * 512) {
            int b = e & 63, g = (e >> 6) & 1023, tp = e >> 16;
            int c = tp * 64 + b;
            size_t tix = ((size_t)(4 * folds + tp) * Hn + g) * 64 + b;
            float tv = __bfloat162float(tb[tix]);
            tv = tanhf(Xf[(size_t)g * 256 + c] + tv);
            tv = tanhf(Xf[(size_t)262144 + (size_t)g * 256 + c] + tv);
            tv = tanhf(Xf[(size_t)524288 + (size_t)g * 256 + c] + tv);
            tb[tix] = __float2bfloat16(tv);
        }
    }
    if (!do_gemm) return;

    const int cq = tid & 127;
    const int rq = tid >> 7;
    const int rbase = __builtin_amdgcn_readfirstlane(g0 + 4 * rq);
    const float* Ar0 = A + (size_t)rbase * Hn;
    const float* Ar1 = Ar0 + Hn;
    const float* Ar2 = Ar0 + 2 * Hn;
    const float* Ar3 = Ar0 + 3 * Hn;
    const float* Bp = Bsrc + (size_t)l * bPanel + bcol0;

    int sk, sc;
    bool sact;
    if (ncols == 256) { sk = tid >> 5; sc = (tid & 31) * 8; sact = true; }
    else              { sk = tid >> 3; sc = (tid & 7) * 8;  sact = (tid < 128); }
    const bool cact = (2 * cq < ncols);

    float acc[4][2] = {};
    float4 p0, p1;

    // stage chunk 0
    if (sact) {
        const float* src = Bp + (size_t)sk * bstride + sc;
        p0 = *(const float4*)(src);
        p1 = *(const float4*)(src + 4);
        *(float4*)&Bsh[0][sk][sc] = p0;
        *(float4*)&Bsh[0][sk][sc + 4] = p1;
    }
    __syncthreads();

    for (int ck = 0; ck < 64; ++ck) {
        if (ck < 63 && sact) {           // prefetch next chunk to regs (T14)
            const float* src = Bp + (size_t)((ck + 1) * 16 + sk) * bstride + sc;
            p0 = *(const float4*)(src);
            p1 = *(const float4*)(src + 4);
        }
        if (cact) {
            const int k0 = ck * 16;
            const float* bs = &Bsh[ck & 1][0][2 * cq];
#pragma unroll
            for (int kk = 0; kk < 16; ++kk) {
                float w0 = Ar0[k0 + kk];
                float w1 = Ar1[k0 + kk];
                float w2 = Ar2[k0 + kk];
                float w3 = Ar3[k0 + kk];
                float2 b2 = *(const float2*)(bs + kk * 256);
                acc[0][0] = fmaf(w0, b2.x, acc[0][0]);
                acc[0][1] = fmaf(w0, b2.y, acc[0][1]);
                acc[1][0] = fmaf(w1, b2.x, acc[1][0]);
                acc[1][1] = fmaf(w1, b2.y, acc[1][1]);
                acc[2][0] = fmaf(w2, b2.x, acc[2][0]);
                acc[2][1] = fmaf(w2, b2.y, acc[2][1]);
                acc[3][0] = fmaf(w3, b2.x, acc[3][0]);
                acc[3][1] = fmaf(w3, b2.y, acc[3][1]);
            }
        }
        if (ck < 63) {
            if (sact) {
                *(float4*)&Bsh[(ck + 1) & 1][sk][sc] = p0;
                *(float4*)&Bsh[(ck + 1) & 1][sk][sc + 4] = p1;
            }
            __syncthreads();
        }
    }

    if (cact) {
#pragma unroll
        for (int i = 0; i < 4; ++i) {
            float av = addRow ? addRow[rbase + i] : 0.0f;
            float* d = dst + (size_t)(rbase + i) * dstride + dcol0 + 2 * cq;
            d[0] = acc[i][0] + av;
            d[1] = acc[i][1] + av;
        }
    }
}

// ------------------------------------------------------------------
// softmax over each 1024-row of logits -> f32 out
// ------------------------------------------------------------------
__global__ __launch_bounds__(256) void softmax_kernel(const float* __restrict__ logits,
                                                      float* __restrict__ out) {
    __shared__ float redm[4];
    __shared__ float reds[4];
    __shared__ float bcast[2];
    int row = blockIdx.x, tid = threadIdx.x;
    const float* in = logits + (size_t)row * On;
    float4 v = *(const float4*)&in[tid * 4];
    float mx = fmaxf(fmaxf(v.x, v.y), fmaxf(v.z, v.w));
#pragma unroll
    for (int o = 32; o > 0; o >>= 1) mx = fmaxf(mx, __shfl_down(mx, o));
    if ((tid & 63) == 0) redm[tid >> 6] = mx;
    __syncthreads();
    if (tid == 0) bcast[0] = fmaxf(fmaxf(redm[0], redm[1]), fmaxf(redm[2], redm[3]));
    __syncthreads();
    float M = bcast[0];
    float e0 = expf(v.x - M), e1 = expf(v.y - M), e2 = expf(v.z - M), e3 = expf(v.w - M);
    float s = e0 + e1 + e2 + e3;
#pragma unroll
    for (int o = 32; o > 0; o >>= 1) s += __shfl_down(s, o);
    if ((tid & 63) == 0) reds[tid >> 6] = s;
    __syncthreads();
    if (tid == 0) bcast[1] = reds[0] + reds[1] + reds[2] + reds[3];
    __syncthreads();
    float inv = 1.0f / bcast[1];
    float4 o4 = make_float4(e0 * inv, e1 * inv, e2 * inv, e3 * inv);
    *(float4*)&out[(size_t)row * On + tid * 4] = o4;
}

// ------------------------------------------------------------------
extern "C" void kernel_launch(void* const* d_in, const int* in_sizes, int n_in,
                              void* d_out, int out_size, void* d_ws, size_t ws_size,
                              hipStream_t stream) {
    const float* x     = (const float*)d_in[0];
    const float* hid   = (const float*)d_in[1];
    const float* fc1_w = (const float*)d_in[2];
    const float* fc1_b = (const float*)d_in[3];
    const float* fc2_w = (const float*)d_in[4];
    const float* fc2_b = (const float*)d_in[5];
    const float* lin_w = (const float*)d_in[6];
    const float* lin_b = (const float*)d_in[7];
    float* out = (float*)d_out;

    char* wsb = (char*)d_ws;
    __hip_bfloat16* tb = (__hip_bfloat16*)wsb;            // 32 MB  [t][g][b]
    float* logits = (float*)(wsb + 33554432ull);          // 64 MB
    float* w2     = (float*)(wsb + 100663296ull);         // 12 MB [3072][1024]
    float* w4     = (float*)(wsb + 113246208ull);         // 12 MB
    float* X      = (float*)(wsb + 125829120ull);         // 2 x 3 MB [l][g][256]
    float* c2     = (float*)(wsb + 132120576ull);         // 12 KB
    float* c4     = (float*)(wsb + 132132864ull);         // 12 KB
    float* h0T    = (float*)(wsb + 132145152ull);         // 768 KB [l][k][b]
    float* h0proj = (float*)(wsb + 132931584ull);         // 256 KB

    float* X0 = X;
    float* X1 = X + 786432;

    prep_kernel<<<48, 256, 0, stream>>>(hid, h0T);
    g1_kernel<<<Bn, 256, 0, stream>>>(hid, fc1_w, fc1_b, h0proj);
    g2_kernel<<<dim3(Sn, Hn / 64), 256, 0, stream>>>(x, fc1_w, h0proj, tb);

    // c2 = W b + b
    cvec_kernel<<<768, 256, 0, stream>>>(lin_w, lin_b, lin_b, c2);
    // W2 = W * W  (4 col passes)
    for (int p = 0; p < 4; ++p)
        gsl_kernel<<<192, 512, 0, stream>>>(lin_w, lin_w, 1048576ull, 1024, p * 256, 256,
                                            w2, 1024, p * 256, nullptr,
                                            tb, nullptr, -1, 1);
    // c4 = W2 c2 + c2
    cvec_kernel<<<768, 256, 0, stream>>>(w2, c2, c2, c4);
    // W4 = W2 * W2
    for (int p = 0; p < 4; ++p)
        gsl_kernel<<<192, 512, 0, stream>>>(w2, w2, 1048576ull, 1024, p * 256, 256,
                                            w4, 1024, p * 256, nullptr,
                                            tb, nullptr, -1, 1);
    // seeds into X0: h1 | h2 | h3 | h4  (cols 0,64,128,192)
    gsl_kernel<<<192, 512, 0, stream>>>(lin_w, h0T, 65536ull, 64, 0, 64,
                                        X0, 256, 0, lin_b, tb, nullptr, -1, 1);
    gsl_kernel<<<192, 512, 0, stream>>>(w2, h0T, 65536ull, 64, 0, 64,
                                        X0, 256, 64, c2, tb, nullptr, -1, 1);
    gsl_kernel<<<192, 512, 0, stream>>>(w4, h0T, 65536ull, 64, 0, 64,
                                        X0, 256, 192, c4, tb, nullptr, -1, 1);
    gsl_kernel<<<192, 512, 0, stream>>>(w2, X0, 262144ull, 256, 0, 64,
                                        X0, 256, 128, c2, tb, nullptr, -1, 1);

    // main: 63 supersteps (X_{s+1} = W4 X_s + c4) with fused fold(batch s)
    for (int s = 0; s < 63; ++s) {
        float* Xin  = (s & 1) ? X1 : X0;
        float* Xout = (s & 1) ? X0 : X1;
        gsl_kernel<<<192, 512, 0, stream>>>(w4, Xin, 262144ull, 256, 0, 256,
                                            Xout, 256, 0, c4, tb, Xin, s, 1);
    }
    // final fold batch 63 (state in X[63&1] = X1)
    gsl_kernel<<<192, 512, 0, stream>>>(w4, X1, 262144ull, 256, 0, 256,
                                        X0, 256, 0, c4, tb, X1, 63, 0);

    g3_kernel<<<dim3(Sn, Hn / 64), 256, 0, stream>>>(tb, fc2_w, fc2_b, logits);
    softmax_kernel<<<Sn * Bn, 256, 0, stream>>>(logits, out);
}